// Round 7
// baseline (381.161 us; speedup 1.0000x reference)
//
#include <hip/hip_runtime.h>
#include <hip/hip_bf16.h>
#include <math.h>

#define B_ 4
#define S_ 2048
#define D_ 2048
#define NH_ 16
#define NKV_ 4
#define HD_ 128

typedef short bf16x8 __attribute__((ext_vector_type(8)));
typedef float f32x4 __attribute__((ext_vector_type(4)));
typedef unsigned u32x4 __attribute__((ext_vector_type(4)));
typedef __hip_bfloat16 bf16;

// async 16B/lane global->LDS: lds dest = uniform base + lane*16
#define ASYNC_CP16(gp, lp)                                                    \
  __builtin_amdgcn_global_load_lds(                                           \
      (const __attribute__((address_space(1))) unsigned int*)(gp),            \
      (__attribute__((address_space(3))) unsigned int*)(lp), 16, 0, 0)

// ---------------- f32 -> bf16 conversion (4 elems/thread) ----------------
__global__ __launch_bounds__(256) void cvt_kernel(const float* __restrict__ in,
                                                  bf16* __restrict__ out, int n4) {
  int i = blockIdx.x * 256 + threadIdx.x;
  if (i >= n4) return;
  float4 v = ((const float4*)in)[i];
  union { ushort4 u; bf16 h[4]; } o;
  o.h[0] = __float2bfloat16(v.x);
  o.h[1] = __float2bfloat16(v.y);
  o.h[2] = __float2bfloat16(v.z);
  o.h[3] = __float2bfloat16(v.w);
  ((ushort4*)out)[i] = o.u;
}

// fused weight conversion: wq (1M float4) | wk (256K) | wv (256K) -> concat dest
__global__ __launch_bounds__(256) void cvt_w_kernel(const float* __restrict__ wq,
                                                    const float* __restrict__ wk,
                                                    const float* __restrict__ wv,
                                                    bf16* __restrict__ out) {
  int i = blockIdx.x * 256 + threadIdx.x;   // 0..1572863
  const float4* src; int off;
  if (i < 1048576)      { src = (const float4*)wq; off = i; }
  else if (i < 1310720) { src = (const float4*)wk; off = i - 1048576; }
  else                  { src = (const float4*)wv; off = i - 1310720; }
  float4 v = src[off];
  union { ushort4 u; bf16 h[4]; } o;
  o.h[0] = __float2bfloat16(v.x);
  o.h[1] = __float2bfloat16(v.y);
  o.h[2] = __float2bfloat16(v.z);
  o.h[3] = __float2bfloat16(v.w);
  ((ushort4*)out)[i] = o.u;
}

// ---------------- fused QKV GEMM + RoPE epilogue (counted-vmcnt pipeline) --
// C[8192,3072] = x @ W^T. BM=256, BN=128, BK=64; 8 waves (4M x 2N, 64x64 each).
// 3 LDS buffers: tile t+2 staged DURING compute of tile t (target buffer was
// last read at t-1, a barrier ago). One s_barrier + s_waitcnt vmcnt(6) per
// K-tile; vmcnt never drained to 0 in steady state (T4). Grid (hblk, mtile) =
// hblk-fastest so 24 consecutive blocks reuse one 1MB A-panel in L2.
// hblk 0..15 -> Q head (rope+scale), 16..19 -> K head (rope), 20..23 -> V.
__global__ __launch_bounds__(512, 2) void gemm_qkv(
    const bf16* __restrict__ A, const bf16* __restrict__ W,
    bf16* __restrict__ qr, bf16* __restrict__ kr, bf16* __restrict__ vlin,
    const float* __restrict__ cosp, const float* __restrict__ sinp,
    float qscale) {
  __shared__ __align__(16) bf16 As[3][256 * 64];   // 3 x 32 KB
  __shared__ __align__(16) bf16 Bs[3][128 * 64];   // 3 x 16 KB
  const int tid = threadIdx.x;
  const int lane = tid & 63, wave = tid >> 6;      // wave 0..7
  const int wm = (wave >> 1) * 64, wn = (wave & 1) * 64;
  const int hblk = blockIdx.x;                     // 0..23 (fast: A-panel reuse)
  const int m0 = blockIdx.y * 256;
  const int n0 = hblk * 128;
  const int quad = lane >> 4, c = lane & 15;
  const int K = 2048;
  const int T = K / 64;                            // 32 K-tiles

  f32x4 acc[4][4] = {};

  // staging: instr i covers rows i*64..i*64+63; wave w covers 8 rows of it.
  // row r = i*64 + wave*8 + (lane>>3); col group swizzled by r&7 = lane>>3&7.
  const int srow = wave * 8 + (lane >> 3);
  const int gcol = ((lane & 7) ^ ((lane >> 3) & 7)) * 8;
  const bf16* Aptr = A + (size_t)(m0 + srow) * K + gcol;
  const bf16* Bptr = W + (size_t)(n0 + srow) * K + gcol;

#define STAGE_A(kb_, buf_, i_)                                                \
  ASYNC_CP16(Aptr + (size_t)(i_) * 64 * K + (kb_),                            \
             &As[buf_][((i_) * 64 + wave * 8) * 64])
#define STAGE_B(kb_, buf_, i_)                                                \
  ASYNC_CP16(Bptr + (size_t)(i_) * 64 * K + (kb_),                            \
             &Bs[buf_][((i_) * 64 + wave * 8) * 64])

  // prologue: stage tile 0 -> buf0, tile 1 -> buf1 (12 loads); wait tile 0.
  {
#pragma unroll
    for (int i = 0; i < 4; i++) STAGE_A(0, 0, i);
#pragma unroll
    for (int i = 0; i < 2; i++) STAGE_B(0, 0, i);
#pragma unroll
    for (int i = 0; i < 4; i++) STAGE_A(64, 1, i);
#pragma unroll
    for (int i = 0; i < 2; i++) STAGE_B(64, 1, i);
    asm volatile("s_waitcnt vmcnt(6)" ::: "memory");
    __builtin_amdgcn_s_barrier();
    __builtin_amdgcn_sched_barrier(0);
  }

  int cur = 0, stg = 2;   // compute buf, stage-target buf ( = (t+2)%3 )
#pragma unroll 1
  for (int t = 0; t < T; ++t) {
    const bf16* Asc = &As[cur][0];
    const bf16* Bsc = &Bs[cur][0];
    const bool st = (t + 2) < T;
    const size_t kb2 = (size_t)(t + 2) * 64;

    // ---- phase 0: kk=0 reads + 3 stage-issues + 16 MFMA
    {
      const int slot = (quad ^ (c & 7)) * 8;
      bf16x8 af[4], bfr[4];
#pragma unroll
      for (int q4 = 0; q4 < 4; q4++) {
        af[q4]  = *(const bf16x8*)(&Asc[(wm + q4 * 16 + c) * 64 + slot]);
        bfr[q4] = *(const bf16x8*)(&Bsc[(wn + q4 * 16 + c) * 64 + slot]);
      }
      if (st) { STAGE_A(kb2, stg, 0); STAGE_A(kb2, stg, 1); STAGE_A(kb2, stg, 2); }
#pragma unroll
      for (int mt = 0; mt < 4; mt++)
#pragma unroll
        for (int nt = 0; nt < 4; nt++)
          acc[mt][nt] = __builtin_amdgcn_mfma_f32_16x16x32_bf16(
              af[mt], bfr[nt], acc[mt][nt], 0, 0, 0);
    }
    // ---- phase 1: kk=1 reads + 3 stage-issues + 16 MFMA
    {
      const int slot = ((4 + quad) ^ (c & 7)) * 8;
      bf16x8 af[4], bfr[4];
#pragma unroll
      for (int q4 = 0; q4 < 4; q4++) {
        af[q4]  = *(const bf16x8*)(&Asc[(wm + q4 * 16 + c) * 64 + slot]);
        bfr[q4] = *(const bf16x8*)(&Bsc[(wn + q4 * 16 + c) * 64 + slot]);
      }
      if (st) { STAGE_A(kb2, stg, 3); STAGE_B(kb2, stg, 0); STAGE_B(kb2, stg, 1); }
#pragma unroll
      for (int mt = 0; mt < 4; mt++)
#pragma unroll
        for (int nt = 0; nt < 4; nt++)
          acc[mt][nt] = __builtin_amdgcn_mfma_f32_16x16x32_bf16(
              af[mt], bfr[nt], acc[mt][nt], 0, 0, 0);
    }

    if (t + 1 < T) {
      // wait: tile t+1 resident (its 6 loads are the oldest; t+2's 6 stay
      // in flight). Tail (t=T-2): nothing newer -> drain to 0.
      if (st) asm volatile("s_waitcnt vmcnt(6)" ::: "memory");
      else    asm volatile("s_waitcnt vmcnt(0)" ::: "memory");
      __builtin_amdgcn_s_barrier();
      __builtin_amdgcn_sched_barrier(0);
    }
    cur = (cur == 2) ? 0 : cur + 1;
    stg = (stg == 2) ? 0 : stg + 1;
  }
#undef STAGE_A
#undef STAGE_B

  __syncthreads();   // main loop done; LDS reusable as scratch

  if (hblk >= 20) {
    // V: direct write to vlin[8192, 512]
    const int colb = (hblk - 20) * 128 + wn;
#pragma unroll
    for (int mt = 0; mt < 4; mt++)
#pragma unroll
      for (int reg = 0; reg < 4; reg++) {
        int m = m0 + wm + mt * 16 + quad * 4 + reg;
        bf16* row = vlin + (size_t)m * (NKV_ * HD_) + colb;
#pragma unroll
        for (int nt = 0; nt < 4; nt++)
          row[nt * 16 + c] = __float2bfloat16(acc[mt][nt][reg]);
      }
  } else {
    // RoPE: odd waves (cols 64..127 of the head) dump f32 to LDS scratch;
    // even waves combine pairs (d, d+64). Scratch = As[0..1] (64 KB).
    float* Sc = (float*)&As[0][0];   // 256 rows x 64 cols f32
    if (wn) {
#pragma unroll
      for (int mt = 0; mt < 4; mt++)
#pragma unroll
        for (int reg = 0; reg < 4; reg++) {
          int lr = wm + mt * 16 + quad * 4 + reg;
#pragma unroll
          for (int nt = 0; nt < 4; nt++)
            Sc[lr * 64 + nt * 16 + c] = acc[mt][nt][reg];
        }
    }
    __syncthreads();
    if (!wn) {
      const float scale = (hblk < 16) ? qscale : 1.0f;
#pragma unroll
      for (int mt = 0; mt < 4; mt++)
#pragma unroll
        for (int reg = 0; reg < 4; reg++) {
          int lr = wm + mt * 16 + quad * 4 + reg;
          int m = m0 + lr;
          int b = m >> 11, s = m & 2047;
          const float* cr = cosp + s * HD_;
          const float* sn = sinp + s * HD_;
          bf16* orow = (hblk < 16)
              ? qr + ((size_t)(b * NH_ + hblk) * S_ + s) * HD_
              : kr + ((size_t)(b * NKV_ + (hblk - 16)) * S_ + s) * HD_;
#pragma unroll
          for (int nt = 0; nt < 4; nt++) {
            int d1 = nt * 16 + c, d2 = d1 + 64;
            float q1 = acc[mt][nt][reg];
            float q2 = Sc[lr * 64 + d1];
            float o1 = (q1 * cr[d1] - q2 * sn[d1]) * scale;
            float o2 = (q2 * cr[d2] + q1 * sn[d2]) * scale;
            orow[d1] = __float2bfloat16(o1);
            orow[d2] = __float2bfloat16(o2);
          }
        }
    }
  }
}

// ---------------- V transpose: vlin[B*S, 512] -> [B,NKV,HD,S] -----
__global__ __launch_bounds__(256) void v_transpose(const bf16* __restrict__ in,
                                                   int instride,
                                                   bf16* __restrict__ out) {
  __shared__ __align__(16) bf16 tile[64][HD_ + 8];
  int bidx = blockIdx.x;
  int st = bidx & 31;
  int kv = (bidx >> 5) & 3;
  int b = bidx >> 7;
  int s0 = st * 64;
  int t = threadIdx.x;
  {
    int row = t >> 2;
    int colb = (t & 3) * 32;
#pragma unroll
    for (int i = 0; i < 4; i++) {
      int col = colb + i * 8;
      *(uint4*)(&tile[row][col]) = *(const uint4*)(
          &in[(size_t)(b * S_ + s0 + row) * instride + kv * HD_ + col]);
    }
  }
  __syncthreads();
  int sl = t & 63, hb = t >> 6;
#pragma unroll
  for (int i = 0; i < 32; i++) {
    int hd = i * 4 + hb;
    out[((size_t)(b * NKV_ + kv) * HD_ + hd) * S_ + s0 + sl] = tile[sl][hd];
  }
}

// ---------------- Flash attention: 32 q-rows/wave (two 16-row groups) -----
// S^T = K*Q^T so each lane owns ONE q (q = lane&15): in-lane softmax.
// Both groups share each K-fragment read (QK) and each V-fragment read (PV):
// LDS traffic per q-row is halved vs 16q/wave. P staged per-group in
// XOR-swizzled LDS. Defer-max (T13). No setprio (lockstep block, m190).
__device__ __forceinline__ void attn_step2(
    const bf16* __restrict__ Ks, const bf16* __restrict__ Vs,
    bf16* __restrict__ PsA, bf16* __restrict__ PsB,
    const bf16x8* qfA, const bf16x8* qfB, f32x4* oA, f32x4* oB,
    float& mA, float& lA, float& mB, float& lB,
    bool diagA, bool diagB, int kb, int qbA, int quad, int c) {
  f32x4 sA[4] = {}, sB[4] = {};
#pragma unroll
  for (int kt = 0; kt < 4; kt++) {
    const int slot = ((kt * 4 + quad) ^ (c & 7)) * 8;
#pragma unroll
    for (int mt = 0; mt < 4; mt++) {
      bf16x8 kf = *(const bf16x8*)(&Ks[(mt * 16 + c) * 128 + slot]);
      sA[mt] = __builtin_amdgcn_mfma_f32_16x16x32_bf16(kf, qfA[kt], sA[mt], 0, 0, 0);
      sB[mt] = __builtin_amdgcn_mfma_f32_16x16x32_bf16(kf, qfB[kt], sB[mt], 0, 0, 0);
    }
  }
  if (diagA) {
    const int qg = qbA + c;
#pragma unroll
    for (int mt = 0; mt < 4; mt++)
#pragma unroll
      for (int r = 0; r < 4; r++)
        if (kb + mt * 16 + quad * 4 + r > qg) sA[mt][r] = -INFINITY;
  }
  if (diagB) {
    const int qg = qbA + 16 + c;
#pragma unroll
    for (int mt = 0; mt < 4; mt++)
#pragma unroll
      for (int r = 0; r < 4; r++)
        if (kb + mt * 16 + quad * 4 + r > qg) sB[mt][r] = -INFINITY;
  }

  // ---- softmax + P pack per group (macro to keep the two paths identical)
#define SOFTMAX_PACK(sacc, m_i, l_i, o, Psw)                                  \
  do {                                                                        \
    f32x4 mx4 = __builtin_elementwise_max(                                    \
        __builtin_elementwise_max(sacc[0], sacc[1]),                          \
        __builtin_elementwise_max(sacc[2], sacc[3]));                         \
    float mx = fmaxf(fmaxf(mx4[0], mx4[1]), fmaxf(mx4[2], mx4[3]));          \
    mx = fmaxf(mx, __shfl_xor(mx, 16, 64));                                   \
    mx = fmaxf(mx, __shfl_xor(mx, 32, 64));                                   \
    if (!__all(mx - m_i <= 8.0f)) {                                           \
      const float mnew = fmaxf(m_i, mx);                                      \
      const float alpha = exp2f(m_i - mnew);                                  \
      m_i = mnew;                                                             \
      l_i *= alpha;                                                           \
      f32x4 av;                                                               \
      av[0] = __shfl(alpha, quad * 4 + 0, 64);                                \
      av[1] = __shfl(alpha, quad * 4 + 1, 64);                                \
      av[2] = __shfl(alpha, quad * 4 + 2, 64);                                \
      av[3] = __shfl(alpha, quad * 4 + 3, 64);                                \
      _Pragma("unroll")                                                       \
      for (int nt = 0; nt < 8; nt++) o[nt] *= av;                             \
    }                                                                         \
    const f32x4 mn4 = {m_i, m_i, m_i, m_i};                                   \
    f32x4 rs4 = {0.f, 0.f, 0.f, 0.f};                                         \
    _Pragma("unroll")                                                         \
    for (int mt = 0; mt < 4; mt++) {                                          \
      f32x4 e = sacc[mt] - mn4;                                               \
      f32x4 p;                                                                \
      p[0] = exp2f(e[0]); p[1] = exp2f(e[1]);                                 \
      p[2] = exp2f(e[2]); p[3] = exp2f(e[3]);                                 \
      rs4 += p;                                                               \
      u32x4 u = __builtin_bit_cast(u32x4, p) + 0x8000u;                       \
      uint2 pk;                                                               \
      pk.x = __builtin_amdgcn_perm(u[1], u[0], 0x07060302u);                  \
      pk.y = __builtin_amdgcn_perm(u[3], u[2], 0x07060302u);                  \
      const int pslot = mt * 2 + (quad >> 1);                                 \
      *(uint2*)(&Psw[c * 64 + ((pslot ^ (c & 7)) << 3) + (quad & 1) * 4]) = pk; \
    }                                                                         \
    float rs = (rs4[0] + rs4[1]) + (rs4[2] + rs4[3]);                         \
    rs += __shfl_xor(rs, 16, 64);                                             \
    rs += __shfl_xor(rs, 32, 64);                                             \
    l_i += rs;                                                                \
  } while (0)

  SOFTMAX_PACK(sA, mA, lA, oA, PsA);
  SOFTMAX_PACK(sB, mB, lB, oB, PsB);
#undef SOFTMAX_PACK

  // ---- PV: shared V-fragment reads feed both groups
#pragma unroll
  for (int kk = 0; kk < 2; kk++) {
    const int psl = (((kk * 4 + quad) ^ (c & 7)) << 3);
    bf16x8 pfA = *(const bf16x8*)(&PsA[c * 64 + psl]);
    bf16x8 pfB = *(const bf16x8*)(&PsB[c * 64 + psl]);
    const int slot = ((kk * 4 + quad) ^ (c & 7)) * 8;
#pragma unroll
    for (int nt = 0; nt < 8; nt++) {
      bf16x8 vf = *(const bf16x8*)(&Vs[(nt * 16 + c) * 64 + slot]);
      oA[nt] = __builtin_amdgcn_mfma_f32_16x16x32_bf16(pfA, vf, oA[nt], 0, 0, 0);
      oB[nt] = __builtin_amdgcn_mfma_f32_16x16x32_bf16(pfB, vf, oB[nt], 0, 0, 0);
    }
  }
}

// 4 waves/block, QBLK=128 (32 q-rows/wave), KVBLK=64, double-buffered K/V,
// paired q-tiles (j then 15-j) -> uniform 36 steps/block. LDS 80 KB ->
// 2 blocks/CU; grid 8x64 = 512 blocks = exactly 2/CU co-resident, no tail.
// launch_bounds(256,2): VGPR cap 256 -> no spill of the 32q/wave state.
__global__ __launch_bounds__(256, 2) void attn_kernel(const bf16* __restrict__ Q,
                                                      const bf16* __restrict__ Kr,
                                                      const bf16* __restrict__ Vt,
                                                      float* __restrict__ O) {
  __shared__ __align__(16) bf16 Ks[2][64 * 128];    // 32 KB
  __shared__ __align__(16) bf16 Vs[2][128 * 64];    // 32 KB
  __shared__ __align__(16) bf16 Ps[4][2][16 * 64];  // 16 KB (A/B per wave)

  const int tid = threadIdx.x, lane = tid & 63, wave = tid >> 6;  // 0..3
  const int quad = lane >> 4, c = lane & 15;
  const int j = blockIdx.x;                 // pair index 0..7
  const int bh = blockIdx.y;
  const int b = bh >> 4, h = bh & 15, kv = h >> 2;
  bf16* PsA = &Ps[wave][0][0];
  bf16* PsB = &Ps[wave][1][0];

  const bf16* kbase = Kr + (size_t)(b * NKV_ + kv) * S_ * HD_;
  const bf16* vbase = Vt + (size_t)(b * NKV_ + kv) * HD_ * S_;

  // staging offsets (elements): 4 waves split K tile (16 rows/wave) and
  // V tile (32 rows/wave); 4 CP16 each.
  int koff[4], voff;
  {
    const int kl = lane >> 4;       // row-in-group for K (4 rows/inst)
    const int ks = lane & 15;
#pragma unroll
    for (int i = 0; i < 4; i++) {
      int r = wave * 16 + i * 4 + kl;
      koff[i] = r * HD_ + ((ks ^ (r & 7)) * 8);
    }
    const int vl = lane >> 3;       // row-in-group for V (8 rows/inst)
    const int vs = lane & 7;
    voff = (wave * 32 + vl) * S_ + ((vs ^ (vl & 7)) * 8);
  }

#define STAGE(kb_, buf_)                                                      \
  do {                                                                        \
    _Pragma("unroll")                                                         \
    for (int i_ = 0; i_ < 4; i_++) {                                          \
      ASYNC_CP16(kbase + (size_t)(kb_) * HD_ + koff[i_],                      \
                 &Ks[buf_][(wave * 16 + i_ * 4) * 128]);                      \
      ASYNC_CP16(vbase + (kb_) + voff + (size_t)(i_ * 8) * S_,                \
                 &Vs[buf_][(wave * 32 + i_ * 8) * 64]);                       \
    }                                                                         \
  } while (0)

  // two sequential passes: q-tile j then 15-j; uniform 36 tile-steps/block.
#pragma unroll 1
  for (int pass = 0; pass < 2; ++pass) {
    const int jj = pass ? (15 - j) : j;    // q-tile of 128 rows
    const int q0 = jj * 128;
    const int qb = q0 + wave * 32;         // group A rows [qb,qb+16), B +16
    const int nsteps = 2 * jj + 2;

    bf16x8 qfA[4], qfB[4];
    {
      const bf16* qpA = Q + ((size_t)(b * NH_ + h) * S_ + qb + c) * HD_;
      const bf16* qpB = qpA + (size_t)16 * HD_;
#pragma unroll
      for (int kt = 0; kt < 4; kt++) {
        qfA[kt] = *(const bf16x8*)(qpA + kt * 32 + quad * 8);
        qfB[kt] = *(const bf16x8*)(qpB + kt * 32 + quad * 8);
      }
    }
    f32x4 oA[8] = {}, oB[8] = {};
    float mA = -INFINITY, lA = 0.f, mB = -INFINITY, lB = 0.f;

    // all waves must be done reading the buffers (prev pass) before overwrite
    __syncthreads();
    STAGE(0, 0);
    int cur = 0;

#pragma unroll 1
    for (int it = 0; it < nsteps; ++it) {
      const int kb = it * 64;
      // barrier drains each wave's own vmcnt(0): tile it resident in buf[cur]
      __syncthreads();
      if (it + 1 < nsteps) STAGE((it + 1) * 64, cur ^ 1);  // in flight
      // skip tiles fully above this wave's 32 q rows (wave-uniform)
      if (kb <= qb + 31)
        attn_step2(&Ks[cur][0], &Vs[cur][0], PsA, PsB, qfA, qfB, oA, oB,
                   mA, lA, mB, lB, kb + 63 > qb, kb + 63 > qb + 16,
                   kb, qb, quad, c);
      cur ^= 1;
    }

    // epilogue (both groups)
    float* obase = O + (size_t)b * S_ * D_ + (size_t)h * HD_;
    {
      float inv[4];
#pragma unroll
      for (int r = 0; r < 4; r++) inv[r] = 1.0f / __shfl(lA, quad * 4 + r, 64);
#pragma unroll
      for (int nt = 0; nt < 8; nt++)
#pragma unroll
        for (int r = 0; r < 4; r++)
          obase[(size_t)(qb + quad * 4 + r) * D_ + nt * 16 + c] = oA[nt][r] * inv[r];
    }
    {
      float inv[4];
#pragma unroll
      for (int r = 0; r < 4; r++) inv[r] = 1.0f / __shfl(lB, quad * 4 + r, 64);
#pragma unroll
      for (int nt = 0; nt < 8; nt++)
#pragma unroll
        for (int r = 0; r < 4; r++)
          obase[(size_t)(qb + 16 + quad * 4 + r) * D_ + nt * 16 + c] = oB[nt][r] * inv[r];
    }
  }
#undef STAGE
}

// ---------------- host launch ----------------
extern "C" void kernel_launch(void* const* d_in, const int* in_sizes, int n_in,
                              void* d_out, int out_size, void* d_ws, size_t ws_size,
                              hipStream_t stream) {
  const float* x    = (const float*)d_in[0];
  const float* cosp = (const float*)d_in[1];
  const float* sinp = (const float*)d_in[2];
  const float* wq   = (const float*)d_in[3];
  const float* wk   = (const float*)d_in[4];
  const float* wv   = (const float*)d_in[5];
  float* out = (float*)d_out;

  char* ws = (char*)d_ws;
  const size_t MB = 1024 * 1024;
  bf16* xb    = (bf16*)(ws + 0);         // 32MB
  bf16* wqkvb = (bf16*)(ws + 32 * MB);   // 12MB: [3072, 2048] concat
  bf16* qr    = (bf16*)(ws + 44 * MB);   // 32MB
  bf16* kr    = (bf16*)(ws + 76 * MB);   // 8MB
  bf16* vlin  = (bf16*)(ws + 84 * MB);   // 8MB
  bf16* vt    = (bf16*)(ws + 92 * MB);   // 8MB

  cvt_kernel<<<16384, 256, 0, stream>>>(x, xb, 4194304);
  cvt_w_kernel<<<6144, 256, 0, stream>>>(wq, wk, wv, wqkvb);

  const float qscale = 1.4426950408889634f / 11.313708498984761f;
  gemm_qkv<<<dim3(24, 32), 512, 0, stream>>>(xb, wqkvb, qr, kr, vlin,
                                             cosp, sinp, qscale);

  v_transpose<<<512, 256, 0, stream>>>(vlin, NKV_ * HD_, vt);

  attn_kernel<<<dim3(8, 64), 256, 0, stream>>>(qr, kr, vt, out);
}

// Round 10
// 378.099 us; speedup vs baseline: 1.0081x; 1.0081x over previous
//
#include <hip/hip_runtime.h>
#include <hip/hip_bf16.h>
#include <math.h>

#define B_ 4
#define S_ 2048
#define D_ 2048
#define NH_ 16
#define NKV_ 4
#define HD_ 128

typedef short bf16x8 __attribute__((ext_vector_type(8)));
typedef float f32x4 __attribute__((ext_vector_type(4)));
typedef unsigned u32x4 __attribute__((ext_vector_type(4)));
typedef __hip_bfloat16 bf16;

// async 16B/lane global->LDS: lds dest = uniform base + lane*16
#define ASYNC_CP16(gp, lp)                                                    \
  __builtin_amdgcn_global_load_lds(                                           \
      (const __attribute__((address_space(1))) unsigned int*)(gp),            \
      (__attribute__((address_space(3))) unsigned int*)(lp), 16, 0, 0)

// ---------------- f32 -> bf16 conversion (4 elems/thread) ----------------
__global__ __launch_bounds__(256) void cvt_kernel(const float* __restrict__ in,
                                                  bf16* __restrict__ out, int n4) {
  int i = blockIdx.x * 256 + threadIdx.x;
  if (i >= n4) return;
  float4 v = ((const float4*)in)[i];
  union { ushort4 u; bf16 h[4]; } o;
  o.h[0] = __float2bfloat16(v.x);
  o.h[1] = __float2bfloat16(v.y);
  o.h[2] = __float2bfloat16(v.z);
  o.h[3] = __float2bfloat16(v.w);
  ((ushort4*)out)[i] = o.u;
}

// fused weight conversion: wq (1M float4) | wk (256K) | wv (256K) -> concat dest
__global__ __launch_bounds__(256) void cvt_w_kernel(const float* __restrict__ wq,
                                                    const float* __restrict__ wk,
                                                    const float* __restrict__ wv,
                                                    bf16* __restrict__ out) {
  int i = blockIdx.x * 256 + threadIdx.x;   // 0..1572863
  const float4* src; int off;
  if (i < 1048576)      { src = (const float4*)wq; off = i; }
  else if (i < 1310720) { src = (const float4*)wk; off = i - 1048576; }
  else                  { src = (const float4*)wv; off = i - 1310720; }
  float4 v = src[off];
  union { ushort4 u; bf16 h[4]; } o;
  o.h[0] = __float2bfloat16(v.x);
  o.h[1] = __float2bfloat16(v.y);
  o.h[2] = __float2bfloat16(v.z);
  o.h[3] = __float2bfloat16(v.w);
  ((ushort4*)out)[i] = o.u;
}

// ---------------- fused QKV GEMM + RoPE epilogue ----------------
// C[8192,3072] = x @ W^T. BM=256, BN=128, BK=64; 8 waves (4M x 2N, 64x64 each).
// 3 LDS buffers, counted vmcnt(6) (T4) + 2 barrier-locked phases per K-tile
// (T3): each phase = {8 ds_read_b128 + 3 stage-issues -> s_barrier ->
// setprio(1) -> 16 MFMA -> setprio(0) -> s_barrier}. Stage of tile t+2 flies
// across both phases; vmcnt(6) at tile end leaves t+2's 6 loads in flight.
// Grid (m-tile, hblk): consecutive blocks share one 512KB B-panel in L2.
// hblk 0..15 -> Q head (rope+scale), 16..19 -> K head (rope), 20..23 -> V.
__global__ __launch_bounds__(512, 2) void gemm_qkv(
    const bf16* __restrict__ A, const bf16* __restrict__ W,
    bf16* __restrict__ qr, bf16* __restrict__ kr, bf16* __restrict__ vlin,
    const float* __restrict__ cosp, const float* __restrict__ sinp,
    float qscale) {
  __shared__ __align__(16) bf16 As[3][256 * 64];   // 3 x 32 KB
  __shared__ __align__(16) bf16 Bs[3][128 * 64];   // 3 x 16 KB
  const int tid = threadIdx.x;
  const int lane = tid & 63, wave = tid >> 6;      // wave 0..7
  const int wm = (wave >> 1) * 64, wn = (wave & 1) * 64;
  const int m0 = blockIdx.x * 256;
  const int hblk = blockIdx.y;
  const int n0 = hblk * 128;
  const int quad = lane >> 4, c = lane & 15;
  const int K = 2048;
  const int T = K / 64;                            // 32 K-tiles

  f32x4 acc[4][4] = {};

  // staging: instr i covers rows i*64..i*64+63; wave w covers 8 rows of it.
  const int srow = wave * 8 + (lane >> 3);
  const int gcol = ((lane & 7) ^ ((lane >> 3) & 7)) * 8;
  const bf16* Aptr = A + (size_t)(m0 + srow) * K + gcol;
  const bf16* Bptr = W + (size_t)(n0 + srow) * K + gcol;

#define STAGE_A(kb_, buf_, i_)                                                \
  ASYNC_CP16(Aptr + (size_t)(i_) * 64 * K + (kb_),                            \
             &As[buf_][((i_) * 64 + wave * 8) * 64])
#define STAGE_B(kb_, buf_, i_)                                                \
  ASYNC_CP16(Bptr + (size_t)(i_) * 64 * K + (kb_),                            \
             &Bs[buf_][((i_) * 64 + wave * 8) * 64])

  // prologue: stage tile 0 -> buf0, tile 1 -> buf1 (12 loads); wait tile 0.
  {
#pragma unroll
    for (int i = 0; i < 4; i++) STAGE_A(0, 0, i);
#pragma unroll
    for (int i = 0; i < 2; i++) STAGE_B(0, 0, i);
#pragma unroll
    for (int i = 0; i < 4; i++) STAGE_A(64, 1, i);
#pragma unroll
    for (int i = 0; i < 2; i++) STAGE_B(64, 1, i);
    asm volatile("s_waitcnt vmcnt(6)" ::: "memory");
    __builtin_amdgcn_s_barrier();
    __builtin_amdgcn_sched_barrier(0);
  }

  int cur = 0, stg = 2;   // compute buf, stage-target buf ( = (t+2)%3 )
#pragma unroll 1
  for (int t = 0; t < T; ++t) {
    const bf16* Asc = &As[cur][0];
    const bf16* Bsc = &Bs[cur][0];
    const bool st = (t + 2) < T;
    const size_t kb2 = (size_t)(t + 2) * 64;

    // ---- phase 0 (kk=0): 8 ds_read + 3 stage -> BAR -> 16 MFMA -> BAR
    {
      const int slot = (quad ^ (c & 7)) * 8;
      bf16x8 af[4], bfr[4];
#pragma unroll
      for (int q4 = 0; q4 < 4; q4++) {
        af[q4]  = *(const bf16x8*)(&Asc[(wm + q4 * 16 + c) * 64 + slot]);
        bfr[q4] = *(const bf16x8*)(&Bsc[(wn + q4 * 16 + c) * 64 + slot]);
      }
      if (st) { STAGE_A(kb2, stg, 0); STAGE_A(kb2, stg, 1); STAGE_A(kb2, stg, 2); }
      __builtin_amdgcn_sched_barrier(0);   // pin reads+stages above the barrier
      __builtin_amdgcn_s_barrier();
      __builtin_amdgcn_s_setprio(1);
#pragma unroll
      for (int mt = 0; mt < 4; mt++)
#pragma unroll
        for (int nt = 0; nt < 4; nt++)
          acc[mt][nt] = __builtin_amdgcn_mfma_f32_16x16x32_bf16(
              af[mt], bfr[nt], acc[mt][nt], 0, 0, 0);
      __builtin_amdgcn_s_setprio(0);
      __builtin_amdgcn_s_barrier();
      __builtin_amdgcn_sched_barrier(0);
    }
    // ---- phase 1 (kk=1): 8 ds_read + 3 stage -> BAR -> 16 MFMA -> vmcnt -> BAR
    {
      const int slot = ((4 + quad) ^ (c & 7)) * 8;
      bf16x8 af[4], bfr[4];
#pragma unroll
      for (int q4 = 0; q4 < 4; q4++) {
        af[q4]  = *(const bf16x8*)(&Asc[(wm + q4 * 16 + c) * 64 + slot]);
        bfr[q4] = *(const bf16x8*)(&Bsc[(wn + q4 * 16 + c) * 64 + slot]);
      }
      if (st) { STAGE_A(kb2, stg, 3); STAGE_B(kb2, stg, 0); STAGE_B(kb2, stg, 1); }
      __builtin_amdgcn_sched_barrier(0);
      __builtin_amdgcn_s_barrier();
      __builtin_amdgcn_s_setprio(1);
#pragma unroll
      for (int mt = 0; mt < 4; mt++)
#pragma unroll
        for (int nt = 0; nt < 4; nt++)
          acc[mt][nt] = __builtin_amdgcn_mfma_f32_16x16x32_bf16(
              af[mt], bfr[nt], acc[mt][nt], 0, 0, 0);
      __builtin_amdgcn_s_setprio(0);
      if (t + 1 < T) {
        // tile t+1 resident (its 6 loads oldest; t+2's 6 stay in flight).
        if (st) asm volatile("s_waitcnt vmcnt(6)" ::: "memory");
        else    asm volatile("s_waitcnt vmcnt(0)" ::: "memory");
      }
      __builtin_amdgcn_s_barrier();
      __builtin_amdgcn_sched_barrier(0);
    }
    cur = (cur == 2) ? 0 : cur + 1;
    stg = (stg == 2) ? 0 : stg + 1;
  }
#undef STAGE_A
#undef STAGE_B

  __syncthreads();   // main loop done; LDS reusable as scratch

  if (hblk >= 20) {
    // V: direct write to vlin[8192, 512]
    const int colb = (hblk - 20) * 128 + wn;
#pragma unroll
    for (int mt = 0; mt < 4; mt++)
#pragma unroll
      for (int reg = 0; reg < 4; reg++) {
        int m = m0 + wm + mt * 16 + quad * 4 + reg;
        bf16* row = vlin + (size_t)m * (NKV_ * HD_) + colb;
#pragma unroll
        for (int nt = 0; nt < 4; nt++)
          row[nt * 16 + c] = __float2bfloat16(acc[mt][nt][reg]);
      }
  } else {
    // RoPE: odd waves (cols 64..127 of the head) dump f32 to LDS scratch;
    // even waves combine pairs (d, d+64). Scratch = As[0..1] (64 KB).
    float* Sc = (float*)&As[0][0];   // 256 rows x 64 cols f32
    if (wn) {
#pragma unroll
      for (int mt = 0; mt < 4; mt++)
#pragma unroll
        for (int reg = 0; reg < 4; reg++) {
          int lr = wm + mt * 16 + quad * 4 + reg;
#pragma unroll
          for (int nt = 0; nt < 4; nt++)
            Sc[lr * 64 + nt * 16 + c] = acc[mt][nt][reg];
        }
    }
    __syncthreads();
    if (!wn) {
      const float scale = (hblk < 16) ? qscale : 1.0f;
#pragma unroll
      for (int mt = 0; mt < 4; mt++)
#pragma unroll
        for (int reg = 0; reg < 4; reg++) {
          int lr = wm + mt * 16 + quad * 4 + reg;
          int m = m0 + lr;
          int b = m >> 11, s = m & 2047;
          const float* cr = cosp + s * HD_;
          const float* sn = sinp + s * HD_;
          bf16* orow = (hblk < 16)
              ? qr + ((size_t)(b * NH_ + hblk) * S_ + s) * HD_
              : kr + ((size_t)(b * NKV_ + (hblk - 16)) * S_ + s) * HD_;
#pragma unroll
          for (int nt = 0; nt < 4; nt++) {
            int d1 = nt * 16 + c, d2 = d1 + 64;
            float q1 = acc[mt][nt][reg];
            float q2 = Sc[lr * 64 + d1];
            float o1 = (q1 * cr[d1] - q2 * sn[d1]) * scale;
            float o2 = (q2 * cr[d2] + q1 * sn[d2]) * scale;
            orow[d1] = __float2bfloat16(o1);
            orow[d2] = __float2bfloat16(o2);
          }
        }
    }
  }
}

// ---------------- V transpose: vlin[B*S, 512] -> [B,NKV,HD,S] -----
__global__ __launch_bounds__(256) void v_transpose(const bf16* __restrict__ in,
                                                   int instride,
                                                   bf16* __restrict__ out) {
  __shared__ __align__(16) bf16 tile[64][HD_ + 8];
  int bidx = blockIdx.x;
  int st = bidx & 31;
  int kv = (bidx >> 5) & 3;
  int b = bidx >> 7;
  int s0 = st * 64;
  int t = threadIdx.x;
  {
    int row = t >> 2;
    int colb = (t & 3) * 32;
#pragma unroll
    for (int i = 0; i < 4; i++) {
      int col = colb + i * 8;
      *(uint4*)(&tile[row][col]) = *(const uint4*)(
          &in[(size_t)(b * S_ + s0 + row) * instride + kv * HD_ + col]);
    }
  }
  __syncthreads();
  int sl = t & 63, hb = t >> 6;
#pragma unroll
  for (int i = 0; i < 32; i++) {
    int hd = i * 4 + hb;
    out[((size_t)(b * NKV_ + kv) * HD_ + hd) * S_ + s0 + sl] = tile[sl][hd];
  }
}

// ---------------- Flash attention: 32 q-rows/wave (two 16-row groups) -----
// S^T = K*Q^T so each lane owns ONE q (q = lane&15): in-lane softmax.
// Both groups share each K-fragment read (QK) and each V-fragment read (PV):
// LDS traffic per q-row is halved vs 16q/wave. P staged per-group in
// XOR-swizzled LDS. Defer-max (T13). No setprio (lockstep block, m190).
__device__ __forceinline__ void attn_step2(
    const bf16* __restrict__ Ks, const bf16* __restrict__ Vs,
    bf16* __restrict__ PsA, bf16* __restrict__ PsB,
    const bf16x8* qfA, const bf16x8* qfB, f32x4* oA, f32x4* oB,
    float& mA, float& lA, float& mB, float& lB,
    bool diagA, bool diagB, int kb, int qbA, int quad, int c) {
  f32x4 sA[4] = {}, sB[4] = {};
#pragma unroll
  for (int kt = 0; kt < 4; kt++) {
    const int slot = ((kt * 4 + quad) ^ (c & 7)) * 8;
#pragma unroll
    for (int mt = 0; mt < 4; mt++) {
      bf16x8 kf = *(const bf16x8*)(&Ks[(mt * 16 + c) * 128 + slot]);
      sA[mt] = __builtin_amdgcn_mfma_f32_16x16x32_bf16(kf, qfA[kt], sA[mt], 0, 0, 0);
      sB[mt] = __builtin_amdgcn_mfma_f32_16x16x32_bf16(kf, qfB[kt], sB[mt], 0, 0, 0);
    }
  }
  if (diagA) {
    const int qg = qbA + c;
#pragma unroll
    for (int mt = 0; mt < 4; mt++)
#pragma unroll
      for (int r = 0; r < 4; r++)
        if (kb + mt * 16 + quad * 4 + r > qg) sA[mt][r] = -INFINITY;
  }
  if (diagB) {
    const int qg = qbA + 16 + c;
#pragma unroll
    for (int mt = 0; mt < 4; mt++)
#pragma unroll
      for (int r = 0; r < 4; r++)
        if (kb + mt * 16 + quad * 4 + r > qg) sB[mt][r] = -INFINITY;
  }

  // ---- softmax + P pack per group (macro to keep the two paths identical)
#define SOFTMAX_PACK(sacc, m_i, l_i, o, Psw)                                  \
  do {                                                                        \
    f32x4 mx4 = __builtin_elementwise_max(                                    \
        __builtin_elementwise_max(sacc[0], sacc[1]),                          \
        __builtin_elementwise_max(sacc[2], sacc[3]));                         \
    float mx = fmaxf(fmaxf(mx4[0], mx4[1]), fmaxf(mx4[2], mx4[3]));          \
    mx = fmaxf(mx, __shfl_xor(mx, 16, 64));                                   \
    mx = fmaxf(mx, __shfl_xor(mx, 32, 64));                                   \
    if (!__all(mx - m_i <= 8.0f)) {                                           \
      const float mnew = fmaxf(m_i, mx);                                      \
      const float alpha = exp2f(m_i - mnew);                                  \
      m_i = mnew;                                                             \
      l_i *= alpha;                                                           \
      f32x4 av;                                                               \
      av[0] = __shfl(alpha, quad * 4 + 0, 64);                                \
      av[1] = __shfl(alpha, quad * 4 + 1, 64);                                \
      av[2] = __shfl(alpha, quad * 4 + 2, 64);                                \
      av[3] = __shfl(alpha, quad * 4 + 3, 64);                                \
      _Pragma("unroll")                                                       \
      for (int nt = 0; nt < 8; nt++) o[nt] *= av;                             \
    }                                                                         \
    const f32x4 mn4 = {m_i, m_i, m_i, m_i};                                   \
    f32x4 rs4 = {0.f, 0.f, 0.f, 0.f};                                         \
    _Pragma("unroll")                                                         \
    for (int mt = 0; mt < 4; mt++) {                                          \
      f32x4 e = sacc[mt] - mn4;                                               \
      f32x4 p;                                                                \
      p[0] = exp2f(e[0]); p[1] = exp2f(e[1]);                                 \
      p[2] = exp2f(e[2]); p[3] = exp2f(e[3]);                                 \
      rs4 += p;                                                               \
      u32x4 u = __builtin_bit_cast(u32x4, p) + 0x8000u;                       \
      uint2 pk;                                                               \
      pk.x = __builtin_amdgcn_perm(u[1], u[0], 0x07060302u);                  \
      pk.y = __builtin_amdgcn_perm(u[3], u[2], 0x07060302u);                  \
      const int pslot = mt * 2 + (quad >> 1);                                 \
      *(uint2*)(&Psw[c * 64 + ((pslot ^ (c & 7)) << 3) + (quad & 1) * 4]) = pk; \
    }                                                                         \
    float rs = (rs4[0] + rs4[1]) + (rs4[2] + rs4[3]);                         \
    rs += __shfl_xor(rs, 16, 64);                                             \
    rs += __shfl_xor(rs, 32, 64);                                             \
    l_i += rs;                                                                \
  } while (0)

  SOFTMAX_PACK(sA, mA, lA, oA, PsA);
  SOFTMAX_PACK(sB, mB, lB, oB, PsB);
#undef SOFTMAX_PACK

  // ---- PV: shared V-fragment reads feed both groups
#pragma unroll
  for (int kk = 0; kk < 2; kk++) {
    const int psl = (((kk * 4 + quad) ^ (c & 7)) << 3);
    bf16x8 pfA = *(const bf16x8*)(&PsA[c * 64 + psl]);
    bf16x8 pfB = *(const bf16x8*)(&PsB[c * 64 + psl]);
    const int slot = ((kk * 4 + quad) ^ (c & 7)) * 8;
#pragma unroll
    for (int nt = 0; nt < 8; nt++) {
      bf16x8 vf = *(const bf16x8*)(&Vs[(nt * 16 + c) * 64 + slot]);
      oA[nt] = __builtin_amdgcn_mfma_f32_16x16x32_bf16(pfA, vf, oA[nt], 0, 0, 0);
      oB[nt] = __builtin_amdgcn_mfma_f32_16x16x32_bf16(pfB, vf, oB[nt], 0, 0, 0);
    }
  }
}

// 4 waves/block, QBLK=128 (32 q-rows/wave), KVBLK=64, double-buffered K/V,
// paired q-tiles (j then 15-j) -> uniform 36 steps/block. LDS 80 KB ->
// 2 blocks/CU; grid 8x64 = 512 blocks = exactly 2/CU co-resident, no tail.
// launch_bounds(256,2): VGPR cap 256 -> no spill of the 32q/wave state.
__global__ __launch_bounds__(256, 2) void attn_kernel(const bf16* __restrict__ Q,
                                                      const bf16* __restrict__ Kr,
                                                      const bf16* __restrict__ Vt,
                                                      float* __restrict__ O) {
  __shared__ __align__(16) bf16 Ks[2][64 * 128];    // 32 KB
  __shared__ __align__(16) bf16 Vs[2][128 * 64];    // 32 KB
  __shared__ __align__(16) bf16 Ps[4][2][16 * 64];  // 16 KB (A/B per wave)

  const int tid = threadIdx.x, lane = tid & 63, wave = tid >> 6;  // 0..3
  const int quad = lane >> 4, c = lane & 15;
  const int j = blockIdx.x;                 // pair index 0..7
  const int bh = blockIdx.y;
  const int b = bh >> 4, h = bh & 15, kv = h >> 2;
  bf16* PsA = &Ps[wave][0][0];
  bf16* PsB = &Ps[wave][1][0];

  const bf16* kbase = Kr + (size_t)(b * NKV_ + kv) * S_ * HD_;
  const bf16* vbase = Vt + (size_t)(b * NKV_ + kv) * HD_ * S_;

  // staging offsets (elements): 4 waves split K tile (16 rows/wave) and
  // V tile (32 rows/wave); 4 CP16 each.
  int koff[4], voff;
  {
    const int kl = lane >> 4;       // row-in-group for K (4 rows/inst)
    const int ks = lane & 15;
#pragma unroll
    for (int i = 0; i < 4; i++) {
      int r = wave * 16 + i * 4 + kl;
      koff[i] = r * HD_ + ((ks ^ (r & 7)) * 8);
    }
    const int vl = lane >> 3;       // row-in-group for V (8 rows/inst)
    const int vs = lane & 7;
    voff = (wave * 32 + vl) * S_ + ((vs ^ (vl & 7)) * 8);
  }

#define STAGE(kb_, buf_)                                                      \
  do {                                                                        \
    _Pragma("unroll")                                                         \
    for (int i_ = 0; i_ < 4; i_++) {                                          \
      ASYNC_CP16(kbase + (size_t)(kb_) * HD_ + koff[i_],                      \
                 &Ks[buf_][(wave * 16 + i_ * 4) * 128]);                      \
      ASYNC_CP16(vbase + (kb_) + voff + (size_t)(i_ * 8) * S_,                \
                 &Vs[buf_][(wave * 32 + i_ * 8) * 64]);                       \
    }                                                                         \
  } while (0)

  // two sequential passes: q-tile j then 15-j; uniform 36 tile-steps/block.
#pragma unroll 1
  for (int pass = 0; pass < 2; ++pass) {
    const int jj = pass ? (15 - j) : j;    // q-tile of 128 rows
    const int q0 = jj * 128;
    const int qb = q0 + wave * 32;         // group A rows [qb,qb+16), B +16
    const int nsteps = 2 * jj + 2;

    bf16x8 qfA[4], qfB[4];
    {
      const bf16* qpA = Q + ((size_t)(b * NH_ + h) * S_ + qb + c) * HD_;
      const bf16* qpB = qpA + (size_t)16 * HD_;
#pragma unroll
      for (int kt = 0; kt < 4; kt++) {
        qfA[kt] = *(const bf16x8*)(qpA + kt * 32 + quad * 8);
        qfB[kt] = *(const bf16x8*)(qpB + kt * 32 + quad * 8);
      }
    }
    f32x4 oA[8] = {}, oB[8] = {};
    float mA = -INFINITY, lA = 0.f, mB = -INFINITY, lB = 0.f;

    // all waves must be done reading the buffers (prev pass) before overwrite
    __syncthreads();
    STAGE(0, 0);
    int cur = 0;

#pragma unroll 1
    for (int it = 0; it < nsteps; ++it) {
      const int kb = it * 64;
      // barrier drains each wave's own vmcnt(0): tile it resident in buf[cur]
      __syncthreads();
      if (it + 1 < nsteps) STAGE((it + 1) * 64, cur ^ 1);  // in flight
      // skip tiles fully above this wave's 32 q rows (wave-uniform)
      if (kb <= qb + 31)
        attn_step2(&Ks[cur][0], &Vs[cur][0], PsA, PsB, qfA, qfB, oA, oB,
                   mA, lA, mB, lB, kb + 63 > qb, kb + 63 > qb + 16,
                   kb, qb, quad, c);
      cur ^= 1;
    }

    // epilogue (both groups)
    float* obase = O + (size_t)b * S_ * D_ + (size_t)h * HD_;
    {
      float inv[4];
#pragma unroll
      for (int r = 0; r < 4; r++) inv[r] = 1.0f / __shfl(lA, quad * 4 + r, 64);
#pragma unroll
      for (int nt = 0; nt < 8; nt++)
#pragma unroll
        for (int r = 0; r < 4; r++)
          obase[(size_t)(qb + quad * 4 + r) * D_ + nt * 16 + c] = oA[nt][r] * inv[r];
    }
    {
      float inv[4];
#pragma unroll
      for (int r = 0; r < 4; r++) inv[r] = 1.0f / __shfl(lB, quad * 4 + r, 64);
#pragma unroll
      for (int nt = 0; nt < 8; nt++)
#pragma unroll
        for (int r = 0; r < 4; r++)
          obase[(size_t)(qb + 16 + quad * 4 + r) * D_ + nt * 16 + c] = oB[nt][r] * inv[r];
    }
  }
#undef STAGE
}

// ---------------- host launch ----------------
extern "C" void kernel_launch(void* const* d_in, const int* in_sizes, int n_in,
                              void* d_out, int out_size, void* d_ws, size_t ws_size,
                              hipStream_t stream) {
  const float* x    = (const float*)d_in[0];
  const float* cosp = (const float*)d_in[1];
  const float* sinp = (const float*)d_in[2];
  const float* wq   = (const float*)d_in[3];
  const float* wk   = (const float*)d_in[4];
  const float* wv   = (const float*)d_in[5];
  float* out = (float*)d_out;

  char* ws = (char*)d_ws;
  const size_t MB = 1024 * 1024;
  bf16* xb    = (bf16*)(ws + 0);         // 32MB
  bf16* wqkvb = (bf16*)(ws + 32 * MB);   // 12MB: [3072, 2048] concat
  bf16* qr    = (bf16*)(ws + 44 * MB);   // 32MB
  bf16* kr    = (bf16*)(ws + 76 * MB);   // 8MB
  bf16* vlin  = (bf16*)(ws + 84 * MB);   // 8MB
  bf16* vt    = (bf16*)(ws + 92 * MB);   // 8MB

  cvt_kernel<<<16384, 256, 0, stream>>>(x, xb, 4194304);
  cvt_w_kernel<<<6144, 256, 0, stream>>>(wq, wk, wv, wqkvb);

  const float qscale = 1.4426950408889634f / 11.313708498984761f;
  gemm_qkv<<<dim3(32, 24), 512, 0, stream>>>(xb, wqkvb, qr, kr, vlin,
                                             cosp, sinp, qscale);

  v_transpose<<<512, 256, 0, stream>>>(vlin, NKV_ * HD_, vt);

  attn_kernel<<<dim3(8, 64), 256, 0, stream>>>(qr, kr, vt, out);
}